// Round 6
// baseline (302.829 us; speedup 1.0000x reference)
//
#include <hip/hip_runtime.h>

// Generalized Lotka-Volterra, RK4, D=64, batch 2048, 255 steps,
// trajectory out (batch, 256, 64) fp32.
//
// Mapping: one 64-lane wave per batch element; lane i owns component i.
// A = -I + E;  f(x) = x .* (r - x + E@x). Diagonal & r exact fp32; E@x in
// packed-f16 v_dot2_f32_f16 (fp32 accumulate). Row i of E lives in 32 VGPRs
// (pinned). Broadcast: DPP-xor1 + v_cvt_pkrtz packs (x_2J, x_2J+1) into 32
// bits on even lanes; 32 v_readlane -> SGPRs; dot2 consumes the SGPR
// DIRECTLY via an "s" asm constraint (VOP3P allows 1 scalar source).
//
// Round-5 lesson: fdot2 builtin forced xs into VGPRs (+32 v_mov/feval) which
// inflated pressure so e[] was demoted to AGPRs (+16 v_accvgpr_read/feval) —
// VGPR_Count=32 and ~3x VALU issue bloat. The "s"-constraint asm removes
// both taxes: per feval ~55 VALU issues (2 pack + 32 readlane + 16 dot2 + 5).

constexpr int D   = 64;   // state dimension == wavefront size
constexpr int NT  = 256;  // trajectory length (255 RK4 steps)
constexpr int WPB = 4;    // waves (= batch elements) per block

typedef _Float16 half2v __attribute__((ext_vector_type(2)));

__device__ __forceinline__ uint32_t pk16(float lo, float hi) {
    return __builtin_bit_cast(uint32_t, __builtin_amdgcn_cvt_pkrtz(lo, hi));
}
// DPP xor-1 on a float (quad_perm [1,0,3,2]).
__device__ __forceinline__ float dpp_xor1(float v) {
    return __int_as_float(__builtin_amdgcn_update_dpp(
        0, __float_as_int(v), 0xB1, 0xF, 0xF, true));
}
// acc += dot2(e_pair, x_pair) with x_pair held in an SGPR (no s->v copy).
#define DOT2S(ACC, E, XS) \
    asm("v_dot2_f32_f16 %0, %1, %2, %0" : "+v"(ACC) : "v"(E), "s"(XS))

// f(xt) = xt * (r - xt + E@xt), wave-cooperative via readlane broadcast.
#define FEVAL(XT, RES)                                                        \
    do {                                                                      \
        const float xt_ = (XT);                                               \
        const uint32_t pair = pk16(xt_, dpp_xor1(xt_)); /* even lanes */      \
        float a0 = ri, a1 = 0.f, a2 = 0.f, a3 = 0.f;                          \
        _Pragma("unroll")                                                     \
        for (int J = 0; J < D / 2; J += 4) {                                  \
            const uint32_t s0 =                                               \
                (uint32_t)__builtin_amdgcn_readlane((int)pair, 2 * (J + 0));  \
            const uint32_t s1 =                                               \
                (uint32_t)__builtin_amdgcn_readlane((int)pair, 2 * (J + 1));  \
            const uint32_t s2 =                                               \
                (uint32_t)__builtin_amdgcn_readlane((int)pair, 2 * (J + 2));  \
            const uint32_t s3 =                                               \
                (uint32_t)__builtin_amdgcn_readlane((int)pair, 2 * (J + 3));  \
            DOT2S(a0, e[J + 0], s0);                                          \
            DOT2S(a1, e[J + 1], s1);                                          \
            DOT2S(a2, e[J + 2], s2);                                          \
            DOT2S(a3, e[J + 3], s3);                                          \
        }                                                                     \
        RES = xt_ * (((a0 + a1) + (a2 + a3)) - xt_);                          \
    } while (0)

__global__ __launch_bounds__(WPB * 64, 2)
void glv_rk4_kernel(const float* __restrict__ x0,
                    const float* __restrict__ r,
                    const float* __restrict__ A,
                    const float* __restrict__ tgrid,
                    float* __restrict__ out)
{
    const int lane = threadIdx.x & 63;
    const int wid  = threadIdx.x >> 6;
    const int b    = blockIdx.x * WPB + wid;   // batch element for this wave

    // E = A + I, row `lane`, packed f16 pairs -> 32 VGPRs (one-time setup).
    uint32_t e[D / 2];
#pragma unroll
    for (int J = 0; J < D / 2; J += 2) {
        const float4 v = *reinterpret_cast<const float4*>(A + lane * D + 2 * J);
        const float e0 = v.x + ((2 * J)     == lane ? 1.0f : 0.0f);
        const float e1 = v.y + ((2 * J + 1) == lane ? 1.0f : 0.0f);
        const float e2 = v.z + ((2 * J + 2) == lane ? 1.0f : 0.0f);
        const float e3 = v.w + ((2 * J + 3) == lane ? 1.0f : 0.0f);
        e[J]     = pk16(e0, e1);
        e[J + 1] = pk16(e2, e3);
    }
    // Anti-sink fence: volatile asm executes exactly once -> E cannot be
    // re-materialized or sunk into the time loop.
#pragma unroll
    for (int J = 0; J < D / 2; ++J)
        asm volatile("" : "+v"(e[J]));

    const float ri = r[lane];
    const float dt = tgrid[1] - tgrid[0];
    const float h2 = 0.5f * dt;
    const float h6 = dt * (1.0f / 6.0f);

    float x = x0[(size_t)b * D + lane];

    float* o = out + (size_t)b * NT * D + lane;
    *o = x; o += D;                            // t = 0 is x0

    for (int t = 1; t < NT; ++t) {
        float k1, k2, k3, k4;
        FEVAL(x, k1);
        FEVAL(fmaf(h2, k1, x), k2);
        FEVAL(fmaf(h2, k2, x), k3);
        FEVAL(fmaf(dt, k3, x), k4);
        x = fmaf(h6, (k1 + k4) + 2.0f * (k2 + k3), x);
        *o = x; o += D;                        // coalesced 256 B/wave store
    }
}

extern "C" void kernel_launch(void* const* d_in, const int* in_sizes, int n_in,
                              void* d_out, int out_size, void* d_ws, size_t ws_size,
                              hipStream_t stream) {
    const float* x0    = (const float*)d_in[0];
    const float* r     = (const float*)d_in[1];
    const float* A     = (const float*)d_in[2];
    const float* tgrid = (const float*)d_in[3];
    float* out         = (float*)d_out;

    const int batch = in_sizes[0] / D;          // 2048
    dim3 grid(batch / WPB);                     // 512 blocks
    dim3 block(WPB * 64);                       // 256 threads = 4 waves

    glv_rk4_kernel<<<grid, block, 0, stream>>>(x0, r, A, tgrid, out);
}